// Round 6
// baseline (506.123 us; speedup 1.0000x reference)
//
#include <hip/hip_runtime.h>
#include <cstdint>
#include <cstddef>

#define TLEN    50
#define BATCH   16
#define D_IN    512
#define SRC_LEN 200
#define VOCAB   20000
#define CVOCAB  20400

typedef __bf16 bf16x8 __attribute__((ext_vector_type(8)));
typedef float  f32x4  __attribute__((ext_vector_type(4)));

#define GEMM_BLOCKS 625                   // 32 vocab cols per block; 625*32 == 20000
#define SCAN_BLOCKS (SRC_LEN * BATCH)     // 3200
#define ZERO_BLOCKS 40

// ---- kernel 0: p_copy[800] = sigmoid(hidden . Wc + bc); hidden -> bf16 ----
__global__ __launch_bounds__(256)
void pc_kernel(const float* __restrict__ hidden,
               const float* __restrict__ Wc,
               const float* __restrict__ bc,
               float* __restrict__ pc,
               __bf16* __restrict__ hbf)
{
    const int row  = blockIdx.x * 4 + (threadIdx.x >> 6);   // 0..799
    const int lane = threadIdx.x & 63;
    const float* h = hidden + (size_t)row * D_IN + lane * 8;
    float4 h0 = *(const float4*)(h);
    float4 h1 = *(const float4*)(h + 4);
    bf16x8 hb;
    hb[0] = (__bf16)h0.x; hb[1] = (__bf16)h0.y;
    hb[2] = (__bf16)h0.z; hb[3] = (__bf16)h0.w;
    hb[4] = (__bf16)h1.x; hb[5] = (__bf16)h1.y;
    hb[6] = (__bf16)h1.z; hb[7] = (__bf16)h1.w;
    *(bf16x8*)(hbf + (size_t)row * D_IN + lane * 8) = hb;

    float4 w0 = *(const float4*)(Wc + lane * 8);
    float4 w1 = *(const float4*)(Wc + lane * 8 + 4);
    float s = h0.x*w0.x + h0.y*w0.y + h0.z*w0.z + h0.w*w0.w
            + h1.x*w1.x + h1.y*w1.y + h1.z*w1.z + h1.w*w1.w;
    #pragma unroll
    for (int o = 1; o < 64; o <<= 1) s += __shfl_xor(s, o);
    if (lane == 0) pc[row] = 1.0f / (1.0f + __expf(-(s + bc[0])));
}

// ---- kernel 1: src_map scan + tail-zero (NO LDS -> full occupancy) --------
// Blocks [0,3200): find the one-hot index of one src_map row with 20
// fully-independent float4 loads per thread (max MLP, one latency round).
// Blocks [3200,3240): zero out cols [20000,20400) of all 800 output rows.
__global__ __launch_bounds__(256)
void scan_kernel(const float* __restrict__ src_map,
                 int* __restrict__ src_ids,
                 float* __restrict__ out)
{
    const int bid = blockIdx.x;
    const int tid = threadIdx.x;
    if (bid < SCAN_BLOCKS) {
        const float4* base = (const float4*)(src_map + (size_t)bid * CVOCAB);
        float4 x[20];
        #pragma unroll
        for (int k = 0; k < 20; ++k) {
            const int i = tid + k * 256;                 // 5100 float4s per row
            x[k] = (i < 5100) ? base[i] : float4{0.f, 0.f, 0.f, 0.f};
        }
        int found = -1;
        #pragma unroll
        for (int k = 0; k < 20; ++k) {
            const int e0 = (tid + k * 256) * 4;
            if (x[k].x > 0.5f) found = e0;
            if (x[k].y > 0.5f) found = e0 + 1;
            if (x[k].z > 0.5f) found = e0 + 2;
            if (x[k].w > 0.5f) found = e0 + 3;
        }
        if (found >= 0) src_ids[bid] = found;            // one finder per row
    } else {
        const int zb = bid - SCAN_BLOCKS;
        const float4 z = {0.f, 0.f, 0.f, 0.f};
        for (int i = tid; i < 2000; i += 256) {
            const int f = zb * 2000 + i;                 // 100 float4s per row
            const int r = f / 100;
            const int c = f % 100;
            *(float4*)(out + (size_t)r * CVOCAB + VOCAB + c * 4) = z;
        }
    }
}

// ---- kernel 2: GEMM (logits, bf16 MFMA) + softmax over batch + scale ------
// B tile (32 cols x 512) in LDS in EXACT fragment order (one ds_read_b128,
// immediate offsets, zero conflicts). Waves split the t-range; two t share
// each B-fragment read (halves LDS-pipe traffic, 4 independent MFMA chains).
// b[v] bias is uniform along the softmax (batch) axis -> cancels; unused.
__global__ __launch_bounds__(256)
void gemm_kernel(const __bf16* __restrict__ hbf,
                 const float* __restrict__ W,
                 const float* __restrict__ pc,
                 float* __restrict__ out)
{
    __shared__ __align__(16) __bf16 Blds[2 * 16 * 64 * 8];  // 32 KB

    const int tid  = threadIdx.x;
    const int lane = tid & 63;
    const int wv   = tid >> 6;
    const int l15  = lane & 15;
    const int q    = lane >> 4;
    const int colbase = blockIdx.x * 32;

    // stage B: 32 (g,c) fragment-planes, 8 per wave
    #pragma unroll
    for (int j = 0; j < 8; ++j) {
        const int p = wv * 8 + j;          // 0..31
        const int g = p >> 4;
        const int c = p & 15;
        const float* src = W + (size_t)(colbase + g * 16 + l15) * D_IN + q * 8 + c * 32;
        float4 f0 = *(const float4*)(src);
        float4 f1 = *(const float4*)(src + 4);
        bf16x8 bf;
        bf[0] = (__bf16)f0.x; bf[1] = (__bf16)f0.y;
        bf[2] = (__bf16)f0.z; bf[3] = (__bf16)f0.w;
        bf[4] = (__bf16)f1.x; bf[5] = (__bf16)f1.y;
        bf[6] = (__bf16)f1.z; bf[7] = (__bf16)f1.w;
        *(bf16x8*)(Blds + (size_t)(g * 16 + c) * 512 + lane * 8) = bf;
    }
    __syncthreads();   // the ONLY barrier

    auto epilogue = [&](int t, f32x4 acc0, f32x4 acc1) {
        float4 pc4 = *(const float4*)(pc + t * 16 + q * 4);
        #pragma unroll
        for (int g = 0; g < 2; ++g) {
            f32x4 acc = g ? acc1 : acc0;
            float mx = -INFINITY;
            #pragma unroll
            for (int r = 0; r < 4; ++r)
                if (q * 4 + r != 1) mx = fmaxf(mx, acc[r]);
            mx = fmaxf(mx, __shfl_xor(mx, 16));
            mx = fmaxf(mx, __shfl_xor(mx, 32));
            float e[4], s = 0.f;
            #pragma unroll
            for (int r = 0; r < 4; ++r) {
                e[r] = (q * 4 + r == 1) ? 0.f : __expf(acc[r] - mx);
                s += e[r];
            }
            s += __shfl_xor(s, 16);
            s += __shfl_xor(s, 32);
            const float inv = 1.0f / s;
            const int v = colbase + g * 16 + l15;
            #pragma unroll
            for (int r = 0; r < 4; ++r) {
                const int b = q * 4 + r;
                out[(size_t)(t * BATCH + b) * CVOCAB + v] = e[r] * inv * (1.0f - pc4[r]);
            }
        }
    };

    // waves split [0,50) as 13/13/12/12
    const int t0 = wv * 12 + (wv < 2 ? wv : 2);           // {0,13,26,38}
    const int t1 = t0 + (wv < 2 ? 13 : 12);               // {13,26,38,50}

    int t = t0;
    for (; t + 1 < t1; t += 2) {
        const __bf16* a0p = hbf + ((size_t)t * BATCH + l15) * D_IN + q * 8;
        const __bf16* a1p = a0p + (size_t)BATCH * D_IN;
        f32x4 acc00 = {0.f,0.f,0.f,0.f}, acc01 = {0.f,0.f,0.f,0.f};
        f32x4 acc10 = {0.f,0.f,0.f,0.f}, acc11 = {0.f,0.f,0.f,0.f};
        #pragma unroll
        for (int c = 0; c < 16; ++c) {
            bf16x8 b0  = *(const bf16x8*)(Blds + (size_t)c * 512 + lane * 8);
            bf16x8 b1  = *(const bf16x8*)(Blds + (size_t)(16 + c) * 512 + lane * 8);
            bf16x8 af0 = *(const bf16x8*)(a0p + c * 32);
            bf16x8 af1 = *(const bf16x8*)(a1p + c * 32);
            acc00 = __builtin_amdgcn_mfma_f32_16x16x32_bf16(af0, b0, acc00, 0, 0, 0);
            acc01 = __builtin_amdgcn_mfma_f32_16x16x32_bf16(af0, b1, acc01, 0, 0, 0);
            acc10 = __builtin_amdgcn_mfma_f32_16x16x32_bf16(af1, b0, acc10, 0, 0, 0);
            acc11 = __builtin_amdgcn_mfma_f32_16x16x32_bf16(af1, b1, acc11, 0, 0, 0);
        }
        epilogue(t, acc00, acc01);
        epilogue(t + 1, acc10, acc11);
    }
    if (t < t1) {
        const __bf16* a0p = hbf + ((size_t)t * BATCH + l15) * D_IN + q * 8;
        f32x4 acc0 = {0.f,0.f,0.f,0.f}, acc1 = {0.f,0.f,0.f,0.f};
        #pragma unroll
        for (int c = 0; c < 16; ++c) {
            bf16x8 b0 = *(const bf16x8*)(Blds + (size_t)c * 512 + lane * 8);
            bf16x8 b1 = *(const bf16x8*)(Blds + (size_t)(16 + c) * 512 + lane * 8);
            bf16x8 af = *(const bf16x8*)(a0p + c * 32);
            acc0 = __builtin_amdgcn_mfma_f32_16x16x32_bf16(af, b0, acc0, 0, 0, 0);
            acc1 = __builtin_amdgcn_mfma_f32_16x16x32_bf16(af, b1, acc1, 0, 0, 0);
        }
        epilogue(t, acc0, acc1);
    }
}

// ---- kernel 3: scatter copy-probs -----------------------------------------
// r=t*16+b; reference's split/stack/transpose sends copy_prob[t,b,:] to
// output row (t'=r%50, b'=r/50). atomicAdd onto already-written out_prob.
__global__ __launch_bounds__(256)
void scatter_copy(const float* __restrict__ attn,
                  const float* __restrict__ pc,
                  const int* __restrict__ src_ids,
                  float* __restrict__ out)
{
    const int p  = blockIdx.x;             // 0..799
    const int si = threadIdx.x;
    if (si >= SRC_LEN) return;
    const int b  = p & 15;
    const size_t obase = (size_t)((p % TLEN) * BATCH + (p / TLEN)) * CVOCAB;
    const int id = src_ids[si * BATCH + b];
    const float val = attn[(size_t)p * SRC_LEN + si] * pc[p];
    if ((unsigned)id < (unsigned)CVOCAB)
        atomicAdd(out + obase + id, val);
}

extern "C" void kernel_launch(void* const* d_in, const int* in_sizes, int n_in,
                              void* d_out, int out_size, void* d_ws, size_t ws_size,
                              hipStream_t stream)
{
    const float* hidden  = (const float*)d_in[0];  // (50,16,512)
    const float* attn    = (const float*)d_in[1];  // (50,16,200)
    const float* src_map = (const float*)d_in[2];  // (200,16,20400) one-hot
    const float* W       = (const float*)d_in[3];  // (20000,512)
    // d_in[4] = b (20000): cancels in softmax over batch -> unused
    const float* Wc      = (const float*)d_in[5];  // (1,512)
    const float* bc      = (const float*)d_in[6];  // (1,)
    float* out   = (float*)d_out;                  // (50,16,20400)

    int*    src_ids = (int*)d_ws;                         // [0, 12800) bytes
    float*  pc      = (float*)((char*)d_ws + 12800);      // [12800, 16000)
    __bf16* hbf     = (__bf16*)((char*)d_ws + 16000);     // 800*512*2 B

    pc_kernel<<<dim3(200), dim3(256), 0, stream>>>(hidden, Wc, bc, pc, hbf);
    scan_kernel<<<dim3(SCAN_BLOCKS + ZERO_BLOCKS), dim3(256), 0, stream>>>(src_map, src_ids, out);
    gemm_kernel<<<dim3(GEMM_BLOCKS), dim3(256), 0, stream>>>(hbf, W, pc, out);
    scatter_copy<<<dim3(TLEN * BATCH), dim3(256), 0, stream>>>(attn, pc, src_ids, out);
}